// Round 10
// baseline (172.035 us; speedup 1.0000x reference)
//
#include <hip/hip_runtime.h>
#include <stdint.h>

#define B_ 2
#define S_ 2048
#define E_ 1024
#define H_ 16
#define D_ 64
#define R_ 16

typedef short s16x8 __attribute__((ext_vector_type(8)));
typedef float f32x4 __attribute__((ext_vector_type(4)));

#define K1_ 0.045084220027780106f   // log2(e)/32
#define K0_ -28.853900817779268f    // -20*log2(e)

// fp32 -> bf16 bits, round-to-nearest (ties away)
__device__ __forceinline__ unsigned short f2bf(float f) {
  union { float f; unsigned u; } v; v.f = f;
  return (unsigned short)((v.u + 0x8000u) >> 16);
}

// async global->LDS, 16B per lane
__device__ __forceinline__ void load_lds16(const void* g, void* l) {
  __builtin_amdgcn_global_load_lds(
      (__attribute__((address_space(1))) void*)(g),
      (__attribute__((address_space(3))) void*)(l), 16, 0, 0);
}

// ---------------- unified prep kernel (unchanged, R4-proven) ----------------
__global__ void k_prep(const float* __restrict__ x,
                       const float* __restrict__ Wq, const float* __restrict__ Wk,
                       const float* __restrict__ Wvd, const float* __restrict__ Wvu,
                       const float* __restrict__ bq, const float* __restrict__ bk,
                       const float* __restrict__ bvd, const float* __restrict__ bvu,
                       unsigned short* __restrict__ xb, unsigned short* __restrict__ Wt,
                       float* __restrict__ ball) {
  __shared__ float T[64][65];
  const int blk = blockIdx.x;
  const int t = threadIdx.x;
  if (blk < 4096) {
    int i = (blk * 256 + t) * 4;
    float4 v = *(const float4*)(x + i);
    ushort4 o;
    o.x = f2bf(v.x); o.y = f2bf(v.y); o.z = f2bf(v.z); o.w = f2bf(v.w);
    *(ushort4*)(xb + i) = o;
  } else if (blk < 4608) {
    const int bb = blk - 4096;
    const int which = bb >> 8;
    const int h = (bb >> 4) & 15;
    const int et = bb & 15;
    const float scl = which ? 1.f : K1_;
    const float* src = (which ? Wk : Wq) + (h * E_ + et * 64) * D_;
#pragma unroll
    for (int pr = 0; pr < 4; ++pr) {
      const int row = pr * 16 + (t >> 4);
      const int col = (t & 15) * 4;
      float4 v = *(const float4*)(src + row * 64 + col);
      T[row][col] = v.x; T[row][col + 1] = v.y; T[row][col + 2] = v.z; T[row][col + 3] = v.w;
    }
    __syncthreads();
#pragma unroll
    for (int pr = 0; pr < 4; ++pr) {
      const int d = pr * 16 + (t >> 4);
      const int ec = (t & 15) * 4;
      ushort4 o;
      o.x = f2bf(T[ec][d] * scl); o.y = f2bf(T[ec + 1][d] * scl);
      o.z = f2bf(T[ec + 2][d] * scl); o.w = f2bf(T[ec + 3][d] * scl);
      *(ushort4*)(Wt + ((which << 10) + h * 64 + d) * 1024 + et * 64 + ec) = o;
    }
  } else if (blk < 8704) {
    const int idx = (blk - 4608) * 256 + t;  // 1M
    const int row = idx >> 10;                // h*64+d
    const int e = idx & 1023;
    const int h = row >> 6, d = row & 63;
    const float4* wd4 = (const float4*)(Wvd + (h << 14) + e * 16);
    const float* wu = Wvu + h * R_ * D_ + d;
    float acc = 0.f;
#pragma unroll
    for (int r4 = 0; r4 < 4; ++r4) {
      float4 a = wd4[r4];
      acc += a.x * wu[(r4 * 4 + 0) * 64];
      acc += a.y * wu[(r4 * 4 + 1) * 64];
      acc += a.z * wu[(r4 * 4 + 2) * 64];
      acc += a.w * wu[(r4 * 4 + 3) * 64];
    }
    Wt[(2048 + row) * 1024 + e] = f2bf(acc);
  } else {
    int n = (blk - 8704) * 256 + t;  // 3072
    int which = n >> 10;
    int hd = n & 1023;
    int h = hd >> 6, d = hd & 63;
    float v;
    if (which == 0) v = bq[hd] * K1_;
    else if (which == 1) v = bk[hd];
    else {
      v = bvu[hd];
#pragma unroll
      for (int r = 0; r < R_; ++r) v += bvd[h * R_ + r] * Wvu[(h * R_ + r) * D_ + d];
    }
    ball[n] = v;
  }
}

// ---------------- fused QKV GEMM (unchanged, R4-proven) ----------------
__global__ __launch_bounds__(256, 2) void k_gemm_qkv(
    const unsigned short* __restrict__ X, const unsigned short* __restrict__ Wt,
    const float* __restrict__ ball,
    unsigned short* __restrict__ Qb, unsigned short* __restrict__ Kb,
    unsigned short* __restrict__ Vb) {
  __shared__ unsigned short As[128 * 32];
  __shared__ unsigned short Bs[128 * 32];
  const int tid = threadIdx.x;
  const int lane = tid & 63, wave = tid >> 6;
  const int quad = lane >> 4, l16 = lane & 15;
  const int mBase = blockIdx.y * 128, nBase = blockIdx.x * 128;
  const int wm = (wave & 1) * 64, wn = (wave >> 1) * 64;
  const int lrow = lane >> 2, lcol = (lane & 3) * 8;

  f32x4 acc[4][4];
#pragma unroll
  for (int mi = 0; mi < 4; ++mi)
#pragma unroll
    for (int ni = 0; ni < 4; ++ni) acc[mi][ni] = (f32x4){0.f, 0.f, 0.f, 0.f};

  for (int k0 = 0; k0 < E_; k0 += 32) {
#pragma unroll
    for (int i = 0; i < 2; ++i) {
      const int r0 = __builtin_amdgcn_readfirstlane((wave + i * 4) * 16);
      load_lds16(X + (mBase + r0 + lrow) * E_ + k0 + lcol, &As[r0 * 32]);
      load_lds16(Wt + (nBase + r0 + lrow) * E_ + k0 + lcol, &Bs[r0 * 32]);
    }
    __syncthreads();
    s16x8 af[4], bfr[4];
#pragma unroll
    for (int mi = 0; mi < 4; ++mi)
      af[mi] = *(const s16x8*)&As[(wm + mi * 16 + l16) * 32 + quad * 8];
#pragma unroll
    for (int ni = 0; ni < 4; ++ni)
      bfr[ni] = *(const s16x8*)&Bs[(wn + ni * 16 + l16) * 32 + quad * 8];
#pragma unroll
    for (int mi = 0; mi < 4; ++mi)
#pragma unroll
      for (int ni = 0; ni < 4; ++ni)
        acc[mi][ni] = __builtin_amdgcn_mfma_f32_16x16x32_bf16(af[mi], bfr[ni], acc[mi][ni], 0, 0, 0);
    __syncthreads();
  }

  const int which = nBase >> 10;  // uniform per block
#pragma unroll
  for (int ni = 0; ni < 4; ++ni) {
    const int n = nBase + wn + ni * 16 + l16;
    const int nh = n & 1023;
    const int h = nh >> 6, d = nh & 63;
    const float bias = ball[n];
#pragma unroll
    for (int mi = 0; mi < 4; ++mi) {
      const int m0 = mBase + wm + mi * 16 + quad * 4;
      const int b = m0 >> 11;
      const int s = m0 & 2047;
      const int bh = b * H_ + h;
      if (which == 2) {
        ushort4 pk;
        pk.x = f2bf(acc[mi][ni][0] + bias);
        pk.y = f2bf(acc[mi][ni][1] + bias);
        pk.z = f2bf(acc[mi][ni][2] + bias);
        pk.w = f2bf(acc[mi][ni][3] + bias);
        *(ushort4*)(Vb + (bh * D_ + d) * S_ + s) = pk;  // transposed store
      } else {
        unsigned short* dst = (which == 0 ? Qb : Kb) + (bh * S_ + s) * D_ + d;
#pragma unroll
        for (int r = 0; r < 4; ++r) dst[r * D_] = f2bf(acc[mi][ni][r] + bias);
      }
    }
  }
}

// ---------------- flash attention (anti-causal: attend t >= s) ----------------
// 2x2 q/t wave partition: wave (qHalf,tHalf) owns 32q x 32t -> K/V fragment
// LDS reads cut 1.8x vs the 16qx64t partition (no 4x duplication).
// K+V double-buffered LDS DMA, one barrier per tile, post-barrier prefetch.
// End-of-kernel cross-tHalf O/l reduction through the REUSED staging LDS.
// 1024 blocks chunk-balanced, 4 blocks/CU (LDS 37.9 KB).
// Fixed-max softmax: Q pre-scaled by K1, QK C-initialized with K0.

__global__ __launch_bounds__(256, 4) void k_attn(
    const unsigned short* __restrict__ Qb, const unsigned short* __restrict__ Kb,
    const unsigned short* __restrict__ Vb, float* __restrict__ out) {
  __shared__ __attribute__((aligned(16))) unsigned char smem[37888];
  unsigned short* const KsB = (unsigned short*)smem;            // [2][4096]
  unsigned short* const VsB = (unsigned short*)(smem + 16384);  // [2][4096]
  unsigned short* const Ps  = (unsigned short*)(smem + 32768);  // [4][16][40]

  const int tid = threadIdx.x;
  const int lane = tid & 63, wave = tid >> 6;
  const int quad = lane >> 4, l16 = lane & 15;
  const int qHalf = wave & 1, tHalf = wave >> 1;
  const int chunk = blockIdx.x >> 8;
  const int j = blockIdx.x & 255;
  int qt = j >> 3;
  if (chunk & 1) qt = 31 - qt;
  const int bh = (j & 7) + 8 * chunk;
  const int q0 = qt * 64;
  const int lrow = lane >> 2, lcol = (lane & 3) * 8;
  const int r0 = __builtin_amdgcn_readfirstlane(wave * 16);
  const f32x4 kvec = {K0_, K0_, K0_, K0_};

  // Q fragments: this wave's 32 q-rows (qHalf), m2 x dc2
  s16x8 qf[2][2];
#pragma unroll
  for (int m = 0; m < 2; ++m)
#pragma unroll
    for (int dc = 0; dc < 2; ++dc)
      qf[m][dc] = *(const s16x8*)(Qb +
          (bh * S_ + q0 + qHalf * 32 + m * 16 + l16) * D_ + dc * 32 + quad * 8);

  f32x4 o[2][4];
#pragma unroll
  for (int m = 0; m < 2; ++m)
#pragma unroll
    for (int dc = 0; dc < 4; ++dc) o[m][dc] = (f32x4){0.f, 0.f, 0.f, 0.f};
  float l_acc[2][4] = {{0.f, 0.f, 0.f, 0.f}, {0.f, 0.f, 0.f, 0.f}};

  unsigned short* const myPs = Ps + wave * (16 * 40);

#define DMA_KV(kt_, b_)                                                          \
  {                                                                              \
    _Pragma("unroll")                                                            \
    for (int hdc = 0; hdc < 2; ++hdc) {                                          \
      load_lds16(Kb + (bh * S_ + (kt_) * 64 + r0 + lrow) * D_ + hdc * 32 + lcol, \
                 &KsB[(b_) * 4096 + hdc * 2048 + r0 * 32]);                      \
      load_lds16(Vb + (bh * D_ + r0 + lrow) * S_ + (kt_) * 64 + hdc * 32 + lcol, \
                 &VsB[(b_) * 4096 + hdc * 2048 + r0 * 32]);                      \
    }                                                                            \
  }

  DMA_KV(qt, 0);
  int buf = 0;
  for (int kt = qt; kt < S_ / 64; ++kt) {
    __syncthreads();  // Ks/Vs[buf] DMA drained; prior reads of buf^1 done
    if (kt + 1 < S_ / 64) DMA_KV(kt + 1, buf ^ 1);

    const unsigned short* Kt = KsB + buf * 4096;
    const unsigned short* Vt = VsB + buf * 4096 + tHalf * 2048;  // its 32-t half
    const bool diag = (kt == qt);
#pragma unroll
    for (int m = 0; m < 2; ++m) {
      // scores for 16 q-rows x 32 keys (this wave's t-half), C-init with K0
#pragma unroll
      for (int nt = 0; nt < 2; ++nt) {
        const int tc = tHalf * 2 + nt;  // 16-t column tile index in the 64
        f32x4 a = __builtin_amdgcn_mfma_f32_16x16x32_bf16(
            qf[m][0], *(const s16x8*)&Kt[(tc * 16 + l16) * 32 + quad * 8], kvec, 0, 0, 0);
        f32x4 sc = __builtin_amdgcn_mfma_f32_16x16x32_bf16(
            qf[m][1], *(const s16x8*)&Kt[2048 + (tc * 16 + l16) * 32 + quad * 8], a, 0, 0, 0);
        if (diag) {
#pragma unroll
          for (int r = 0; r < 4; ++r) {
            const int t = tc * 16 + l16;
            const int q = qHalf * 32 + m * 16 + quad * 4 + r;
            if (t < q) sc[r] = -200.f;
          }
        }
#pragma unroll
        for (int r = 0; r < 4; ++r) {
          float p = exp2f(sc[r]);
          l_acc[m][r] += p;
          myPs[(quad * 4 + r) * 40 + nt * 16 + l16] =
              (unsigned short)(__float_as_uint(p) >> 16);
        }
      }
      // PV over this wave's 32 t: P A-frag from per-wave LDS (no barrier)
      s16x8 pf = *(const s16x8*)&myPs[l16 * 40 + quad * 8];
#pragma unroll
      for (int dc = 0; dc < 4; ++dc) {
        s16x8 vb = *(const s16x8*)&Vt[(dc * 16 + l16) * 32 + quad * 8];
        o[m][dc] = __builtin_amdgcn_mfma_f32_16x16x32_bf16(pf, vb, o[m][dc], 0, 0, 0);
      }
    }
    buf ^= 1;
  }
#undef DMA_KV

  // l: reduce over the 16 t-lanes of each row (both halves do this)
#pragma unroll
  for (int off = 1; off < 16; off <<= 1)
#pragma unroll
    for (int m = 0; m < 2; ++m)
#pragma unroll
      for (int r = 0; r < 4; ++r) l_acc[m][r] += __shfl_xor(l_acc[m][r], off);

  // cross-tHalf reduction via reused staging LDS
  __syncthreads();
  float* const obuf = (float*)smem;             // [2 qHalf][64 d][36 pad]
  float* const lbuf = (float*)(smem + 18432);   // [64]
  if (tHalf == 1) {
#pragma unroll
    for (int m = 0; m < 2; ++m) {
#pragma unroll
      for (int dc = 0; dc < 4; ++dc)
        *(f32x4*)&obuf[(qHalf * 64 + dc * 16 + l16) * 36 + m * 16 + quad * 4] = o[m][dc];
      if (l16 == 0)
        *(float4*)&lbuf[qHalf * 32 + m * 16 + quad * 4] =
            make_float4(l_acc[m][0], l_acc[m][1], l_acc[m][2], l_acc[m][3]);
    }
  }
  __syncthreads();
  if (tHalf == 0) {
    const int b = bh >> 4, h = bh & 15;
#pragma unroll
    for (int m = 0; m < 2; ++m) {
      float rinv[4];
#pragma unroll
      for (int r = 0; r < 4; ++r)
        rinv[r] = 1.f / (l_acc[m][r] + lbuf[qHalf * 32 + m * 16 + quad * 4 + r]);
#pragma unroll
      for (int dc = 0; dc < 4; ++dc) {
        f32x4 oo = o[m][dc] +
            *(const f32x4*)&obuf[(qHalf * 64 + dc * 16 + l16) * 36 + m * 16 + quad * 4];
#pragma unroll
        for (int r = 0; r < 4; ++r) {
          const int s = q0 + qHalf * 32 + m * 16 + quad * 4 + r;
          out[(b * S_ + s) * (H_ * D_) + h * D_ + dc * 16 + l16] = oo[r] * rinv[r];
        }
      }
    }
  }
}

// ---------------- launch ----------------

extern "C" void kernel_launch(void* const* d_in, const int* in_sizes, int n_in,
                              void* d_out, int out_size, void* d_ws, size_t ws_size,
                              hipStream_t stream) {
  const float* x   = (const float*)d_in[0];
  const float* Wq  = (const float*)d_in[1];
  const float* bq  = (const float*)d_in[2];
  const float* Wk  = (const float*)d_in[3];
  const float* bk  = (const float*)d_in[4];
  const float* Wvd = (const float*)d_in[5];
  const float* bvd = (const float*)d_in[6];
  const float* Wvu = (const float*)d_in[7];
  const float* bvu = (const float*)d_in[8];
  float* out = (float*)d_out;

  char* ws = (char*)d_ws;
  unsigned short* xb   = (unsigned short*)(ws);                    // 8 MB
  unsigned short* Wt   = (unsigned short*)(ws + (8u << 20));       // 6 MB
  float*          ball = (float*)(ws + (14u << 20));               // 12 KB
  unsigned short* Qb   = (unsigned short*)(ws + (15u << 20));      // 8 MB
  unsigned short* Kb   = (unsigned short*)(ws + (23u << 20));      // 8 MB
  unsigned short* Vb   = (unsigned short*)(ws + (31u << 20));      // 8 MB (transposed)

  k_prep<<<8716, 256, 0, stream>>>(x, Wq, Wk, Wvd, Wvu, bq, bk, bvd, bvu, xb, Wt, ball);
  k_gemm_qkv<<<dim3(3072 / 128, 4096 / 128), 256, 0, stream>>>(xb, Wt, ball, Qb, Kb, Vb);
  k_attn<<<1024, 256, 0, stream>>>(Qb, Kb, Vb, out);
}